// Round 3
// baseline (229.759 us; speedup 1.0000x reference)
//
#include <hip/hip_runtime.h>

#define B_    8
#define CIN_  64
#define COUT_ 64
#define H_    256
#define W_    256
#define HW_   65536

typedef __attribute__((ext_vector_type(8)))  short short8;    // 8 bf16 = 4 VGPRs
typedef __attribute__((ext_vector_type(16))) float f32x16;

static __device__ __forceinline__ unsigned short f2bf(float f) {
    union { float f; unsigned u; } v; v.f = f;
    unsigned r = (v.u + 0x7FFFu + ((v.u >> 16) & 1u)) >> 16;  // RNE
    return (unsigned short)r;
}

// LDS halfword index with bank swizzle: s = px slot (row*36+col), ciL = 0..31.
// 16B chunk (ciL>>3) XOR'd with (s + s>>2)&3: spreads banks for both the
// strided reads (s step 1) and the transpose writes (s step 2).
static __device__ __forceinline__ int swzH(int s, int ciL) {
    return s * 32 + (((ciL >> 3) ^ ((s + (s >> 2)) & 3)) << 3) + (ciL & 7);
}

// ---------------------------------------------------------------------------
// Kernel 1: aggregate weights -> bf16, layout aggb[b][tap][co][ci]
// ---------------------------------------------------------------------------
__global__ __launch_bounds__(256) void prep_weights_kernel(
    const float* __restrict__ att,     // [B][10]
    const float* __restrict__ weight,  // [COUT][CIN][9]
    const float* __restrict__ tb, const float* __restrict__ tq,
    const float* __restrict__ tn, const float* __restrict__ tx,
    const float* __restrict__ mb, const float* __restrict__ mq,
    const float* __restrict__ mn, const float* __restrict__ mx,
    unsigned short* __restrict__ aggb) // [B][9][COUT][CIN] bf16
{
    int idx = blockIdx.x * 256 + threadIdx.x;
    if (idx >= B_ * 9 * COUT_ * CIN_) return;
    int b    = idx / (9 * COUT_ * CIN_);
    int rem  = idx - b * (9 * COUT_ * CIN_);
    int tap  = rem / (COUT_ * CIN_);
    int rem2 = rem & (COUT_ * CIN_ - 1);
    int co   = rem2 >> 6;
    int ci   = rem2 & 63;

    int r  = (co * CIN_ + ci) * 9 + tap;   // [co][ci][kh][kw]
    int cc = co * CIN_ + ci;

    float a0 = att[b * 10 + 0];
    float a1 = att[b * 10 + 1];
    float a2 = att[b * 10 + 2];
    float val = weight[r]
              + tb[r] * mb[cc] * a1
              + tq[r] * mq[cc] * a2
              + (tn[r] * mn[cc] + tx[r] * mx[cc]) * a0;
    aggb[idx] = f2bf(val);
}

// ---------------------------------------------------------------------------
// Kernel 2: implicit-GEMM conv via mfma_f32_32x32x16_bf16.
// Block: 512 thr = 8 waves. Tile: 64 cout x (8 rows x 32 cols), one batch.
// Two ci-phases (32 ci each); LDS x-tile [10 rows][36 cols][32 ci] bf16.
// Wave w: cg = w&1 (32 couts), rows r0 = (w>>1)*2 .. +1, all 32 cols.
// D layout (32x32): col=lane&31 -> pixel (32 contiguous floats per store
// segment = full 128B lines), row=(reg&3)+8*(reg>>2)+4*(lane>>5) -> cout.
// ---------------------------------------------------------------------------
__global__ __launch_bounds__(512, 5) void conv_kernel(
    const float* __restrict__ x,            // [B][CIN][H][W] fp32
    const unsigned short* __restrict__ aggb,// [B][9][COUT][CIN] bf16
    const float* __restrict__ bias,         // [COUT]
    float* __restrict__ out)                // [B][COUT][H][W] fp32
{
    __shared__ unsigned short xs[10 * 36 * 32];   // 23040 B

    const int t = threadIdx.x;

    // XCD swizzle: 2048 blocks, 8 XCDs -> each XCD gets one full batch
    // (weights 74KB + x-plane stay L2-local).
    int bid = blockIdx.x;
    int sw  = (bid & 7) * 256 + (bid >> 3);
    int bz  = sw >> 8;            // batch 0..7
    int rem = sw & 255;
    int by  = rem >> 3;           // row tile 0..31
    int bx  = rem & 7;            // col tile 0..7
    const int x0 = bx * 32;
    const int y0 = by * 8;

    const int l  = t & 63;
    const int w  = t >> 6;        // wave 0..7
    const int cg = w & 1;         // cout group (32 couts)
    const int r0 = (w >> 1) * 2;  // rows r0, r0+1
    const int lp = l & 31;        // pixel lane
    const int lk = l >> 5;        // k-half

    const float* xb = x + (size_t)bz * CIN_ * HW_;
    const unsigned short* wb = aggb + (size_t)bz * 9 * COUT_ * CIN_;

    f32x16 acc[2];
#pragma unroll
    for (int i = 0; i < 16; ++i) { acc[0][i] = 0.f; acc[1][i] = 0.f; }

#pragma unroll
    for (int p = 0; p < 2; ++p) {
        const int cb = p * 32;

        // ---- stage: 10 rows x 32 ci x 18 float2 segs = 5760 jobs ----
        for (int it = 0; it < 12; ++it) {
            int j = it * 512 + t;
            if (j < 5760) {
                int q   = j / 18;
                int seg = j - q * 18;
                int ci  = q & 31;
                int row = q >> 5;            // 0..9
                int gy  = y0 + row - 1;
                int gx  = x0 + seg * 2 - 2;  // even -> float2 never straddles bounds
                float2 v; v.x = 0.f; v.y = 0.f;
                if ((unsigned)gy < H_ && (unsigned)gx < W_)
                    v = *(const float2*)(xb + (size_t)(cb + ci) * HW_ + gy * W_ + gx);
                int s0 = row * 36 + seg * 2;
                xs[swzH(s0,     ci)] = f2bf(v.x);
                xs[swzH(s0 + 1, ci)] = f2bf(v.y);
            }
        }
        __syncthreads();

        // ---- compute: 9 taps x 2 k-steps ----
#pragma unroll
        for (int tap = 0; tap < 9; ++tap) {
            const int kh = tap / 3;
            const int kw = tap - kh * 3;
#pragma unroll
            for (int ks = 0; ks < 2; ++ks) {
                // A: W[co][k], co = cg*32+lp, k = ks*16 + lk*8 + j  (global, L2-hot)
                short8 af = *(const short8*)&wb[(size_t)(tap * COUT_ + cg * 32 + lp) * CIN_
                                                + cb + ks * 16 + lk * 8];
                const int chunk = ks * 2 + lk;
#pragma unroll
                for (int rr = 0; rr < 2; ++rr) {
                    int s = (r0 + rr + kh) * 36 + lp + kw + 1;
                    int hidx = s * 32 + ((chunk ^ ((s + (s >> 2)) & 3)) << 3);
                    short8 bf = *(const short8*)&xs[hidx];
                    acc[rr] = __builtin_amdgcn_mfma_f32_32x32x16_bf16(af, bf, acc[rr], 0, 0, 0);
                }
            }
        }
        __syncthreads();
    }

    // ---- epilogue: bias + store (full 128B line segments) ----
    const size_t ob = (size_t)bz * COUT_ * HW_;
#pragma unroll
    for (int g = 0; g < 16; ++g) {
        int co = cg * 32 + (g & 3) + 8 * (g >> 2) + 4 * lk;
        float bs = bias[co];
#pragma unroll
        for (int rr = 0; rr < 2; ++rr) {
            __builtin_nontemporal_store(acc[rr][g] + bs,
                &out[ob + (size_t)co * HW_ + (size_t)(y0 + r0 + rr) * W_ + x0 + lp]);
        }
    }
}

extern "C" void kernel_launch(void* const* d_in, const int* in_sizes, int n_in,
                              void* d_out, int out_size, void* d_ws, size_t ws_size,
                              hipStream_t stream) {
    const float* x      = (const float*)d_in[0];
    const float* att    = (const float*)d_in[1];
    const float* weight = (const float*)d_in[2];
    const float* tb     = (const float*)d_in[3];
    const float* tq     = (const float*)d_in[4];
    const float* tn     = (const float*)d_in[5];
    const float* tx     = (const float*)d_in[6];
    const float* mb     = (const float*)d_in[7];
    const float* mq     = (const float*)d_in[8];
    const float* mn     = (const float*)d_in[9];
    const float* mx     = (const float*)d_in[10];
    const float* bias   = (const float*)d_in[11];

    unsigned short* aggb = (unsigned short*)d_ws;   // 294912 bf16 = 590 KB
    float* outp = (float*)d_out;

    int n_agg = B_ * 9 * COUT_ * CIN_;
    prep_weights_kernel<<<(n_agg + 255) / 256, 256, 0, stream>>>(
        att, weight, tb, tq, tn, tx, mb, mq, mn, mx, aggb);

    conv_kernel<<<2048, 512, 0, stream>>>(x, aggb, bias, outp);
}

// Round 4
// 115.622 us; speedup vs baseline: 1.9872x; 1.9872x over previous
//
#include <hip/hip_runtime.h>

#define B_    8
#define CIN_  64
#define COUT_ 64
#define H_    256
#define W_    256
#define HW_   65536

typedef __attribute__((ext_vector_type(8)))  short short8;    // 8 bf16 = 4 VGPRs
typedef __attribute__((ext_vector_type(16))) float f32x16;

static __device__ __forceinline__ unsigned short f2bf(float f) {
    union { float f; unsigned u; } v; v.f = f;
    unsigned r = (v.u + 0x7FFFu + ((v.u >> 16) & 1u)) >> 16;  // RNE
    return (unsigned short)r;
}

// ---------------------------------------------------------------------------
// Kernel 1: aggregate weights -> bf16, layout aggb[b][tap][co][ci]
// ---------------------------------------------------------------------------
__global__ __launch_bounds__(256) void prep_weights_kernel(
    const float* __restrict__ att,     // [B][10]
    const float* __restrict__ weight,  // [COUT][CIN][9]
    const float* __restrict__ tb, const float* __restrict__ tq,
    const float* __restrict__ tn, const float* __restrict__ tx,
    const float* __restrict__ mb, const float* __restrict__ mq,
    const float* __restrict__ mn, const float* __restrict__ mx,
    unsigned short* __restrict__ aggb) // [B][9][COUT][CIN] bf16
{
    int idx = blockIdx.x * 256 + threadIdx.x;
    if (idx >= B_ * 9 * COUT_ * CIN_) return;
    int b    = idx / (9 * COUT_ * CIN_);
    int rem  = idx - b * (9 * COUT_ * CIN_);
    int tap  = rem / (COUT_ * CIN_);
    int rem2 = rem & (COUT_ * CIN_ - 1);
    int co   = rem2 >> 6;
    int ci   = rem2 & 63;

    int r  = (co * CIN_ + ci) * 9 + tap;   // [co][ci][kh][kw]
    int cc = co * CIN_ + ci;

    float a0 = att[b * 10 + 0];
    float a1 = att[b * 10 + 1];
    float a2 = att[b * 10 + 2];
    float val = weight[r]
              + tb[r] * mb[cc] * a1
              + tq[r] * mq[cc] * a2
              + (tn[r] * mn[cc] + tx[r] * mx[cc]) * a0;
    aggb[idx] = f2bf(val);
}

// ---------------------------------------------------------------------------
// Kernel 2: implicit-GEMM conv via mfma_f32_32x32x16_bf16.
// Block: 512 thr = 8 waves. Tile: 64 cout x (8 rows x 64 cols), one batch.
// Two ci-phases (32 ci each). LDS: x-tile [s=row*66+col][32 ci] (42.2 KB) +
// weights [sw=tap*64+co][32 ci] (36.9 KB) = 79.1 KB -> 2 blocks/CU.
// Swizzle: 16B chunk (ci>>3) ^= (slot>>1)&3  -> conflict-free ds_read_b128
// on both A (co-consecutive lanes) and B (pixel-consecutive lanes).
// Wave w owns output row y0+w, all 64 co (2 A-frags) x 64 px (2 B-frags):
// 4 MFMAs per 2A+2B LDS reads. A-swizzle folds to per-lane constant ->
// all A addresses are base + compile-time immediate.
// ---------------------------------------------------------------------------
__global__ __launch_bounds__(512, 4) void conv_kernel(
    const float* __restrict__ x,            // [B][CIN][H][W] fp32
    const unsigned short* __restrict__ aggb,// [B][9][COUT][CIN] bf16
    const float* __restrict__ bias,         // [COUT]
    float* __restrict__ out)                // [B][COUT][H][W] fp32
{
    __shared__ unsigned short xs[660 * 32];   // 42240 B
    __shared__ unsigned short ws[576 * 32];   // 36864 B

    const int t = threadIdx.x;

    // XCD swizzle: 1024 blocks, xcd = batch; within XCD consecutive blocks
    // are row-neighbors (halo rows reuse in that XCD's L2).
    int bid = blockIdx.x;
    int bz  = bid & 7;            // batch
    int idx = bid >> 3;           // 0..127
    int ct  = idx >> 5;           // 0..3  col tile
    int rt  = idx & 31;           // 0..31 row tile
    const int x0 = ct * 64;
    const int y0 = rt * 8;

    const int l  = t & 63;
    const int w  = t >> 6;        // wave 0..7 -> output row
    const int lp = l & 31;        // pixel / co lane
    const int lk = l >> 5;        // k-half

    const float* xb = x + (size_t)bz * CIN_ * HW_;
    const unsigned short* wb = aggb + (size_t)bz * 9 * COUT_ * CIN_;

    f32x16 acc[2][2];             // [co-group][pixel-group]
#pragma unroll
    for (int i = 0; i < 16; ++i) {
        acc[0][0][i] = 0.f; acc[0][1][i] = 0.f;
        acc[1][0][i] = 0.f; acc[1][1][i] = 0.f;
    }

    // Per-lane constant A byte-offsets (swizzle depends only on lp).
    const int swzA   = (lp >> 1) & 3;
    const int baseA0 = lp * 64 + (((0 + lk) ^ swzA) << 4);   // ks=0
    const int baseA1 = lp * 64 + (((2 + lk) ^ swzA) << 4);   // ks=1
    const int sB0    = w * 66 + lp;

#pragma unroll
    for (int p = 0; p < 2; ++p) {
        const int cb = p * 32;

        // ---- stage weights: 2304 jobs = (tap*64+co) x 4 chunks ----
        for (int it = 0; it < 5; ++it) {
            int j = it * 512 + t;
            if (j < 2304) {
                int cg  = j & 3;
                int sw_ = j >> 2;                      // tap*64+co
                uint4 v = *(const uint4*)&wb[sw_ * 64 + cb + cg * 8];
                int chunk = cg ^ ((sw_ >> 1) & 3);
                *(uint4*)&ws[sw_ * 32 + (chunk << 3)] = v;
            }
        }
        // ---- stage x: 5280 jobs = 8 ci-quads x 660 slots ----
        for (int it = 0; it < 11; ++it) {
            int j = it * 512 + t;
            if (j < 5280) {
                int cg4 = j / 660;                     // ci quad 0..7
                int s   = j - cg4 * 660;               // slot = row*66+col
                int row = s / 66;
                int col = s - row * 66;
                int gy  = y0 + row - 1;
                int gx  = x0 + col - 1;
                float f0 = 0.f, f1 = 0.f, f2 = 0.f, f3 = 0.f;
                if ((unsigned)gy < H_ && (unsigned)gx < W_) {
                    const float* src = xb + (size_t)(cb + cg4 * 4) * HW_ + gy * W_ + gx;
                    f0 = src[0]; f1 = src[HW_]; f2 = src[2 * HW_]; f3 = src[3 * HW_];
                }
                unsigned lo = (unsigned)f2bf(f0) | ((unsigned)f2bf(f1) << 16);
                unsigned hi = (unsigned)f2bf(f2) | ((unsigned)f2bf(f3) << 16);
                int chunk = (cg4 >> 1) ^ ((s >> 1) & 3);
                int h = s * 32 + (chunk << 3) + (cg4 & 1) * 4;
                *(uint2*)&xs[h] = make_uint2(lo, hi);
            }
        }
        __syncthreads();

        // ---- compute: 9 taps x 2 k-steps x (2A + 2B reads -> 4 MFMA) ----
#pragma unroll
        for (int tap = 0; tap < 9; ++tap) {
            const int kh = tap / 3;
            const int kw = tap - kh * 3;
            const int aT = tap * 4096;                 // bytes
#pragma unroll
            for (int ks = 0; ks < 2; ++ks) {
                const int baseA = (ks ? baseA1 : baseA0) + aT;
                short8 a0 = *(const short8*)((const char*)ws + baseA);
                short8 a1 = *(const short8*)((const char*)ws + baseA + 2048);
                const int ksl = ks * 2 + lk;
#pragma unroll
                for (int pb = 0; pb < 2; ++pb) {
                    int s  = sB0 + kh * 66 + kw + pb * 32;
                    int hb = s * 32 + ((ksl ^ ((s >> 1) & 3)) << 3);
                    short8 bfv = *(const short8*)&xs[hb];
                    acc[0][pb] = __builtin_amdgcn_mfma_f32_32x32x16_bf16(a0, bfv, acc[0][pb], 0, 0, 0);
                    acc[1][pb] = __builtin_amdgcn_mfma_f32_32x32x16_bf16(a1, bfv, acc[1][pb], 0, 0, 0);
                }
            }
        }
        __syncthreads();
    }

    // ---- epilogue: bias + store (full 128B line segments, no nt) ----
    const size_t ob = (size_t)bz * COUT_ * HW_ + (size_t)(y0 + w) * W_ + x0;
#pragma unroll
    for (int cg = 0; cg < 2; ++cg) {
#pragma unroll
        for (int g = 0; g < 16; ++g) {
            int co = cg * 32 + (g & 3) + 8 * (g >> 2) + 4 * lk;
            float bs = bias[co];
            out[ob + (size_t)co * HW_ + lp]      = acc[cg][0][g] + bs;
            out[ob + (size_t)co * HW_ + 32 + lp] = acc[cg][1][g] + bs;
        }
    }
}

extern "C" void kernel_launch(void* const* d_in, const int* in_sizes, int n_in,
                              void* d_out, int out_size, void* d_ws, size_t ws_size,
                              hipStream_t stream) {
    const float* x      = (const float*)d_in[0];
    const float* att    = (const float*)d_in[1];
    const float* weight = (const float*)d_in[2];
    const float* tb     = (const float*)d_in[3];
    const float* tq     = (const float*)d_in[4];
    const float* tn     = (const float*)d_in[5];
    const float* tx     = (const float*)d_in[6];
    const float* mb     = (const float*)d_in[7];
    const float* mq     = (const float*)d_in[8];
    const float* mn     = (const float*)d_in[9];
    const float* mx     = (const float*)d_in[10];
    const float* bias   = (const float*)d_in[11];

    unsigned short* aggb = (unsigned short*)d_ws;   // 294912 bf16 = 590 KB
    float* outp = (float*)d_out;

    int n_agg = B_ * 9 * COUT_ * CIN_;
    prep_weights_kernel<<<(n_agg + 255) / 256, 256, 0, stream>>>(
        att, weight, tb, tq, tn, tx, mb, mq, mn, mx, aggb);

    conv_kernel<<<1024, 512, 0, stream>>>(x, aggb, bias, outp);
}

// Round 5
// 111.470 us; speedup vs baseline: 2.0612x; 1.0372x over previous
//
#include <hip/hip_runtime.h>

#define B_    8
#define CIN_  64
#define COUT_ 64
#define H_    256
#define W_    256
#define HW_   65536

typedef __attribute__((ext_vector_type(8)))  short short8;    // 8 bf16 = 4 VGPRs
typedef __attribute__((ext_vector_type(16))) float f32x16;

static __device__ __forceinline__ unsigned short f2bf(float f) {
    union { float f; unsigned u; } v; v.f = f;
    unsigned r = (v.u + 0x7FFFu + ((v.u >> 16) & 1u)) >> 16;  // RNE
    return (unsigned short)r;
}

// async global->LDS, 16B per lane. LDS dest must be wave-uniform base + lane*16.
static __device__ __forceinline__ void gload16(void* lds, const void* g) {
    __builtin_amdgcn_global_load_lds(
        (const __attribute__((address_space(1))) unsigned int*)g,
        (__attribute__((address_space(3))) unsigned int*)lds, 16, 0, 0);
}

// ws layout (bytes):
//   [0,       589824)  aggb  [B][9][COUT][CIN] bf16
//   [589824,  589952)  zero pad (128 B)
//   [1048576, +64MiB)  xT    [B][HW][CIN] bf16
#define WS_PAD_OFF 589824
#define WS_XT_OFF  1048576

// ---------------------------------------------------------------------------
// Kernel 1: aggregate weights -> bf16, layout aggb[b][tap][co][ci]; zero pad.
// ---------------------------------------------------------------------------
__global__ __launch_bounds__(256) void prep_weights_kernel(
    const float* __restrict__ att,     // [B][10]
    const float* __restrict__ weight,  // [COUT][CIN][9]
    const float* __restrict__ tb, const float* __restrict__ tq,
    const float* __restrict__ tn, const float* __restrict__ tx,
    const float* __restrict__ mb, const float* __restrict__ mq,
    const float* __restrict__ mn, const float* __restrict__ mx,
    unsigned short* __restrict__ aggb) // [B][9][COUT][CIN] bf16
{
    int idx = blockIdx.x * 256 + threadIdx.x;
    if (idx < 64) aggb[294912 + idx] = 0;          // zero pad region
    if (idx >= B_ * 9 * COUT_ * CIN_) return;
    int b    = idx / (9 * COUT_ * CIN_);
    int rem  = idx - b * (9 * COUT_ * CIN_);
    int tap  = rem / (COUT_ * CIN_);
    int rem2 = rem & (COUT_ * CIN_ - 1);
    int co   = rem2 >> 6;
    int ci   = rem2 & 63;

    int r  = (co * CIN_ + ci) * 9 + tap;   // [co][ci][kh][kw]
    int cc = co * CIN_ + ci;

    float a0 = att[b * 10 + 0];
    float a1 = att[b * 10 + 1];
    float a2 = att[b * 10 + 2];
    float val = weight[r]
              + tb[r] * mb[cc] * a1
              + tq[r] * mq[cc] * a2
              + (tn[r] * mn[cc] + tx[r] * mx[cc]) * a0;
    aggb[idx] = f2bf(val);
}

// ---------------------------------------------------------------------------
// Kernel 2: transpose+convert x [B][CIN][HW] fp32 -> xT [B][HW][CIN] bf16.
// Block: 256 thr, tile = 64 pixels x 64 ci for one batch. Fully coalesced
// loads (256B/wave); 16B stores (128B lines merge across adjacent instrs).
// ---------------------------------------------------------------------------
__global__ __launch_bounds__(256) void transpose_kernel(
    const float* __restrict__ x, unsigned short* __restrict__ xT)
{
    __shared__ unsigned short tile[64 * 72];   // 9216 B, row stride 144B (16B-aligned)

    int bid = blockIdx.x;
    int b   = bid >> 10;
    int p0  = (bid & 1023) << 6;
    int t   = threadIdx.x;
    int l   = t & 63;       // pixel lane
    int g   = t >> 6;       // wave -> ci group g*16..+15

    const float* xp = x + (((size_t)(b * CIN_ + g * 16)) << 16) + p0 + l;
    unsigned pk[8];
#pragma unroll
    for (int i = 0; i < 8; ++i) {
        float v0 = xp[(size_t)(2 * i) << 16];
        float v1 = xp[(size_t)(2 * i + 1) << 16];
        pk[i] = (unsigned)f2bf(v0) | ((unsigned)f2bf(v1) << 16);
    }
    *(uint4*)&tile[l * 72 + g * 16]     = make_uint4(pk[0], pk[1], pk[2], pk[3]);
    *(uint4*)&tile[l * 72 + g * 16 + 8] = make_uint4(pk[4], pk[5], pk[6], pk[7]);
    __syncthreads();

    unsigned short* dst = xT + (((size_t)b << 16) + p0) * 64;
#pragma unroll
    for (int it = 0; it < 2; ++it) {
        int p = t >> 2;
        int c = (t & 3) + it * 4;
        uint4 v = *(const uint4*)&tile[p * 72 + c * 8];
        *(uint4*)&dst[(size_t)p * 64 + c * 8] = v;
    }
}

// ---------------------------------------------------------------------------
// Kernel 3: implicit-GEMM conv via mfma_f32_32x32x16_bf16.
// Block: 512 thr = 8 waves. Tile: 64 cout x (8 rows x 64 cols), one batch.
// Two ci-phases (32 ci each). LDS: x-tile [672 slots][64B] (43008 B, slots
// >=660 are wave-uniform-masked padding) + weights [576][64B] (36864 B)
// = 79.9 KB -> 2 blocks/CU. ALL staging via global_load_lds(16B): linear LDS
// dest, source pre-swizzled by chunk ^= (slot>>1)&3, OOB lanes -> zero pad.
// Compute loop identical to round 4 (reads swizzled, conflict-minimal).
// ---------------------------------------------------------------------------
__global__ __launch_bounds__(512, 4) void conv_kernel(
    const unsigned char* __restrict__ wsb,  // d_ws base
    const float* __restrict__ bias,         // [COUT]
    float* __restrict__ out)                // [B][COUT][H][W] fp32
{
    __shared__ unsigned short xs[672 * 32];   // 43008 B
    __shared__ unsigned short ws[576 * 32];   // 36864 B

    const int t = threadIdx.x;

    // XCD swizzle: 1024 blocks, xcd = bid&7 = batch.
    int bid = blockIdx.x;
    int bz  = bid & 7;            // batch
    int idx = bid >> 3;           // 0..127
    int ct  = idx >> 5;           // 0..3  col tile
    int rt  = idx & 31;           // 0..31 row tile
    const int x0 = ct * 64;
    const int y0 = rt * 8;

    const int l  = t & 63;
    const int w  = t >> 6;        // wave 0..7 -> output row
    const int lp = l & 31;        // pixel / co lane
    const int lk = l >> 5;        // k-half

    const unsigned char* wbB  = wsb + (size_t)bz * (9 * COUT_ * CIN_ * 2);
    const unsigned char* xTB  = wsb + WS_XT_OFF + (size_t)bz * ((size_t)HW_ * CIN_ * 2);
    const unsigned char* zpad = wsb + WS_PAD_OFF;

    // ---- precompute per-thread staging sources (half=0; half=1 adds 64B) ----
    const unsigned char* wsrc[5];
#pragma unroll
    for (int i = 0; i < 5; ++i) {
        int j  = i * 512 + t;
        int sw = j >> 2;                               // may reach 767 on i=4 (masked)
        int c2 = (t & 3) ^ ((sw >> 1) & 3);
        wsrc[i] = (sw < 576) ? wbB + (size_t)sw * 128 + c2 * 16 : zpad;
    }
    const unsigned char* xsrc[6];
#pragma unroll
    for (int i = 0; i < 6; ++i) {
        int j  = i * 512 + t;
        int s  = j >> 2;                               // 0..671
        int row = s / 66;
        int col = s - row * 66;
        int gy  = y0 + row - 1;
        int gx  = x0 + col - 1;
        int c2  = (t & 3) ^ ((s >> 1) & 3);
        bool v  = (s < 660) && ((unsigned)gy < H_) && ((unsigned)gx < W_);
        xsrc[i] = v ? xTB + ((size_t)(gy * W_ + gx)) * 128 + c2 * 16 : zpad;
    }

    // Per-lane constant A byte-offsets (swizzle folds to lane constant).
    const int swzA   = (lp >> 1) & 3;
    const int baseA0 = lp * 64 + (((0 + lk) ^ swzA) << 4);   // ks=0
    const int baseA1 = lp * 64 + (((2 + lk) ^ swzA) << 4);   // ks=1
    const int sB0    = w * 66 + lp;

    f32x16 acc[2][2];             // [co-group][pixel-group]
#pragma unroll
    for (int i = 0; i < 16; ++i) {
        acc[0][0][i] = 0.f; acc[0][1][i] = 0.f;
        acc[1][0][i] = 0.f; acc[1][1][i] = 0.f;
    }

#pragma unroll
    for (int p = 0; p < 2; ++p) {
        const int hofs = p * 64;   // +64B into each 128B row for ci-half 1

        // ---- stage weights: 2304 16B transfers (iter 4: waves 0..3 only) ----
#pragma unroll
        for (int i = 0; i < 5; ++i) {
            if (i < 4 || t < 256)
                gload16((char*)ws + (i * 512 + t) * 16, wsrc[i] + hofs);
        }
        // ---- stage x: 2688 16B transfers (iter 5: waves 0..1 only) ----
#pragma unroll
        for (int i = 0; i < 6; ++i) {
            if (i < 5 || t < 128)
                gload16((char*)xs + (i * 512 + t) * 16, xsrc[i] + hofs);
        }
        __syncthreads();   // drains vmcnt + barrier

        // ---- compute: 9 taps x 2 k-steps x (2A + 2B reads -> 4 MFMA) ----
#pragma unroll
        for (int tap = 0; tap < 9; ++tap) {
            const int kh = tap / 3;
            const int kw = tap - kh * 3;
            const int aT = tap * 4096;                 // bytes
#pragma unroll
            for (int ks = 0; ks < 2; ++ks) {
                const int baseA = (ks ? baseA1 : baseA0) + aT;
                short8 a0 = *(const short8*)((const char*)ws + baseA);
                short8 a1 = *(const short8*)((const char*)ws + baseA + 2048);
                const int ksl = ks * 2 + lk;
#pragma unroll
                for (int pb = 0; pb < 2; ++pb) {
                    int s  = sB0 + kh * 66 + kw + pb * 32;
                    int hb = s * 32 + ((ksl ^ ((s >> 1) & 3)) << 3);
                    short8 bfv = *(const short8*)&xs[hb];
                    acc[0][pb] = __builtin_amdgcn_mfma_f32_32x32x16_bf16(a0, bfv, acc[0][pb], 0, 0, 0);
                    acc[1][pb] = __builtin_amdgcn_mfma_f32_32x32x16_bf16(a1, bfv, acc[1][pb], 0, 0, 0);
                }
            }
        }
        __syncthreads();
    }

    // ---- epilogue: bias + store (full 128B line segments) ----
    const size_t ob = (size_t)bz * COUT_ * HW_ + (size_t)(y0 + w) * W_ + x0;
#pragma unroll
    for (int cg = 0; cg < 2; ++cg) {
#pragma unroll
        for (int g = 0; g < 16; ++g) {
            int co = cg * 32 + (g & 3) + 8 * (g >> 2) + 4 * lk;
            float bs = bias[co];
            out[ob + (size_t)co * HW_ + lp]      = acc[cg][0][g] + bs;
            out[ob + (size_t)co * HW_ + 32 + lp] = acc[cg][1][g] + bs;
        }
    }
}

extern "C" void kernel_launch(void* const* d_in, const int* in_sizes, int n_in,
                              void* d_out, int out_size, void* d_ws, size_t ws_size,
                              hipStream_t stream) {
    const float* x      = (const float*)d_in[0];
    const float* att    = (const float*)d_in[1];
    const float* weight = (const float*)d_in[2];
    const float* tb     = (const float*)d_in[3];
    const float* tq     = (const float*)d_in[4];
    const float* tn     = (const float*)d_in[5];
    const float* tx     = (const float*)d_in[6];
    const float* mb     = (const float*)d_in[7];
    const float* mq     = (const float*)d_in[8];
    const float* mn     = (const float*)d_in[9];
    const float* mx     = (const float*)d_in[10];
    const float* bias   = (const float*)d_in[11];

    unsigned short* aggb = (unsigned short*)d_ws;
    unsigned short* xT   = (unsigned short*)((unsigned char*)d_ws + WS_XT_OFF);
    float* outp = (float*)d_out;

    int n_agg = B_ * 9 * COUT_ * CIN_;
    prep_weights_kernel<<<(n_agg + 255) / 256, 256, 0, stream>>>(
        att, weight, tb, tq, tn, tx, mb, mq, mn, mx, aggb);

    transpose_kernel<<<8192, 256, 0, stream>>>(x, xT);

    conv_kernel<<<1024, 512, 0, stream>>>((const unsigned char*)d_ws, bias, outp);
}

// Round 6
// 105.380 us; speedup vs baseline: 2.1803x; 1.0578x over previous
//
#include <hip/hip_runtime.h>

#define B_    8
#define CIN_  64
#define COUT_ 64
#define H_    256
#define W_    256
#define HW_   65536

typedef __attribute__((ext_vector_type(8)))  short short8;    // 8 bf16 = 4 VGPRs
typedef __attribute__((ext_vector_type(16))) float f32x16;

static __device__ __forceinline__ unsigned short f2bf(float f) {
    union { float f; unsigned u; } v; v.f = f;
    unsigned r = (v.u + 0x7FFFu + ((v.u >> 16) & 1u)) >> 16;  // RNE
    return (unsigned short)r;
}

// async global->LDS, 16B per lane. LDS dest = wave-uniform base + lane*16.
static __device__ __forceinline__ void gload16(void* lds, const void* g) {
    __builtin_amdgcn_global_load_lds(
        (const __attribute__((address_space(1))) unsigned int*)g,
        (__attribute__((address_space(3))) unsigned int*)lds, 16, 0, 0);
}

// inline-asm barrier: also a compiler memory fence (prevents motion of
// ds/global ops across it, unlike the bare builtin).
static __device__ __forceinline__ void bar() {
    asm volatile("s_barrier" ::: "memory");
}

// ws layout (bytes):
//   [0,       589824)  aggb  [B][9][COUT][CIN] bf16
//   [589824,  589952)  zero pad (128 B)
//   [1048576, +64MiB)  xT    [B][HW][CIN] bf16
#define WS_PAD_OFF 589824
#define WS_XT_OFF  1048576

// ---------------------------------------------------------------------------
// Kernel 1 (fused): blocks 0..8191 transpose+convert x -> xT[b][pix][ci] bf16;
// blocks 8192..9343 aggregate weights -> aggb[b][tap][co][ci] bf16 + zero pad.
// ---------------------------------------------------------------------------
__global__ __launch_bounds__(256) void prep_kernel(
    const float* __restrict__ x,
    const float* __restrict__ att, const float* __restrict__ weight,
    const float* __restrict__ tb, const float* __restrict__ tq,
    const float* __restrict__ tn, const float* __restrict__ tx,
    const float* __restrict__ mb, const float* __restrict__ mq,
    const float* __restrict__ mn, const float* __restrict__ mx,
    unsigned short* __restrict__ aggb, unsigned short* __restrict__ xT)
{
    __shared__ unsigned short tile[64 * 72];   // transpose staging

    int bid = blockIdx.x;
    int t   = threadIdx.x;

    if (bid >= 8192) {                         // ---- weights part ----
        int idx = (bid - 8192) * 256 + t;
        if (idx < 64) aggb[294912 + idx] = 0;  // zero pad region (128 B)
        if (idx >= B_ * 9 * COUT_ * CIN_) return;
        int b    = idx / (9 * COUT_ * CIN_);
        int rem  = idx - b * (9 * COUT_ * CIN_);
        int tap  = rem / (COUT_ * CIN_);
        int rem2 = rem & (COUT_ * CIN_ - 1);
        int co   = rem2 >> 6;
        int ci   = rem2 & 63;
        int r  = (co * CIN_ + ci) * 9 + tap;   // [co][ci][kh][kw]
        int cc = co * CIN_ + ci;
        float a0 = att[b * 10 + 0];
        float a1 = att[b * 10 + 1];
        float a2 = att[b * 10 + 2];
        float val = weight[r]
                  + tb[r] * mb[cc] * a1
                  + tq[r] * mq[cc] * a2
                  + (tn[r] * mn[cc] + tx[r] * mx[cc]) * a0;
        aggb[idx] = f2bf(val);
        return;
    }

    // ---- transpose part: tile = 64 pixels x 64 ci of one batch ----
    int b  = bid >> 10;
    int p0 = (bid & 1023) << 6;
    int l  = t & 63;       // pixel lane
    int g  = t >> 6;       // wave -> ci group g*16..+15

    const float* xp = x + (((size_t)(b * CIN_ + g * 16)) << 16) + p0 + l;
    unsigned pk[8];
#pragma unroll
    for (int i = 0; i < 8; ++i) {
        float v0 = xp[(size_t)(2 * i) << 16];
        float v1 = xp[(size_t)(2 * i + 1) << 16];
        pk[i] = (unsigned)f2bf(v0) | ((unsigned)f2bf(v1) << 16);
    }
    *(uint4*)&tile[l * 72 + g * 16]     = make_uint4(pk[0], pk[1], pk[2], pk[3]);
    *(uint4*)&tile[l * 72 + g * 16 + 8] = make_uint4(pk[4], pk[5], pk[6], pk[7]);
    __syncthreads();

    unsigned short* dst = xT + (((size_t)b << 16) + p0) * 64;
#pragma unroll
    for (int it = 0; it < 2; ++it) {
        int p = t >> 2;
        int c = (t & 3) + it * 4;
        uint4 v = *(const uint4*)&tile[p * 72 + c * 8];
        *(uint4*)&dst[(size_t)p * 64 + c * 8] = v;
    }
}

// ---------------------------------------------------------------------------
// Kernel 2: implicit-GEMM conv, 4-phase (16-ci) double-buffered pipeline.
// Block: 512 thr = 8 waves. Tile: 64 cout x (8 rows x 64 cols), one batch.
// LDS (79.9 KB -> 2 blocks/CU):
//   xlds[2][chunk(2)][slot(672)] x 16B  : B operand, conflict-free contiguous
//   wlds[tap(9)][chunk(4)][co(64)] x 16B: A operand, conflict-free contiguous
// All staging via global_load_lds(16B), linear LDS dest, layout permutation
// folded into per-lane global source addresses. Pipeline per phase p:
//   issue stage(p+1) -> s_waitcnt vmcnt(cnt_newest) -> bar -> compute(p) -> bar
// so phase p+1's loads stay in flight across compute(p) (T3/T4-lite).
// ---------------------------------------------------------------------------
__global__ __launch_bounds__(512, 4) void conv_kernel(
    const unsigned char* __restrict__ wsb,  // d_ws base
    const float* __restrict__ bias,         // [COUT]
    float* __restrict__ out)                // [B][COUT][H][W] fp32
{
    __shared__ __align__(16) unsigned short xlds[2][10752];  // 2 x 21504 B
    __shared__ __align__(16) unsigned short wlds[18432];     // 36864 B

    const int t = threadIdx.x;

    // XCD swizzle: 1024 blocks, xcd = bid&7 = batch.
    int bid = blockIdx.x;
    int bz  = bid & 7;            // batch
    int idx = bid >> 3;           // 0..127
    int ct  = idx >> 5;           // 0..3  col tile
    int rt  = idx & 31;           // 0..31 row tile
    const int x0 = ct * 64;
    const int y0 = rt * 8;

    const int l  = t & 63;
    const int w  = t >> 6;        // wave 0..7 -> output row
    const int lp = l & 31;        // pixel / co lane
    const int lk = l >> 5;        // k-half

    const unsigned char* wbB  = wsb + (size_t)bz * (9 * COUT_ * CIN_ * 2);
    const unsigned char* xTB  = wsb + WS_XT_OFF + (size_t)bz * ((size_t)HW_ * CIN_ * 2);
    const unsigned char* zpad = wsb + WS_PAD_OFF;

    // ---- per-thread staging sources ----
    // X: transfer j = i*512+t (j<1344): chunk c=j/672, slot s=j%672.
    //    slot s -> pixel (y0+s/66-1, x0+s%66-1); src 16B = xT[pix]*128+q*32+c*16.
    const unsigned char* xsrc[3];
#pragma unroll
    for (int i = 0; i < 3; ++i) {
        int j   = i * 512 + t;
        int c   = (j >= 672) ? 1 : 0;
        int s   = j - c * 672;
        int row = s / 66;
        int col = s - row * 66;
        int gy  = y0 + row - 1;
        int gx  = x0 + col - 1;
        bool v  = (s < 660) && ((unsigned)gy < H_) && ((unsigned)gx < W_);
        xsrc[i] = v ? (xTB + ((size_t)(gy * W_ + gx)) * 128 + c * 16) : zpad;
    }
    // W: transfer j = i*512+t (j<2304): co=j&63, chunk=(j>>6)&3, tap=j>>8.
    const unsigned char* wsrc[5];
#pragma unroll
    for (int i = 0; i < 5; ++i) {
        int j   = i * 512 + t;
        int co  = j & 63;
        int ch  = (j >> 6) & 3;
        int tap = j >> 8;
        wsrc[i] = (j < 2304) ? (wbB + (size_t)(tap * 64 + co) * 128 + ch * 16) : zpad;
    }

    auto issue_x = [&](unsigned short* buf, int q) {
        gload16((char*)buf + t * 16,         xsrc[0] + q * 32);
        gload16((char*)buf + 8192 + t * 16,  xsrc[1] + q * 32);
        if (t < 320)                                       // waves 0-4 only
            gload16((char*)buf + 16384 + t * 16, xsrc[2] + q * 32);
    };
    auto issue_w = [&](int off) {
        gload16((char*)wlds + t * 16,         wsrc[0] + off);
        gload16((char*)wlds + 8192 + t * 16,  wsrc[1] + off);
        gload16((char*)wlds + 16384 + t * 16, wsrc[2] + off);
        gload16((char*)wlds + 24576 + t * 16, wsrc[3] + off);
        if (t < 256)                                       // waves 0-3 only
            gload16((char*)wlds + 32768 + t * 16, wsrc[4] + off);
    };
    // Wait so that only the newest X batch may remain in flight.
    auto waitx = [&]() {
        if (t < 320) { asm volatile("s_waitcnt vmcnt(3)" ::: "memory"); }
        else         { asm volatile("s_waitcnt vmcnt(2)" ::: "memory"); }
    };

    f32x16 acc[2][2];             // [co-group][pixel-group]
#pragma unroll
    for (int i = 0; i < 16; ++i) {
        acc[0][0][i] = 0.f; acc[0][1][i] = 0.f;
        acc[1][0][i] = 0.f; acc[1][1][i] = 0.f;
    }

    // compute one 16-ci phase from buffer `buf`, W k-half h (0=lo,1=hi).
    auto compute = [&](const unsigned short* buf, const int h) {
        const char* Ab = (const char*)wlds + h * 2048 + lk * 1024 + lp * 16;
        const char* Bb = (const char*)buf + lk * 10752 + (w * 66 + lp) * 16;
#pragma unroll
        for (int tap = 0; tap < 9; ++tap) {
            const int kh = tap / 3;
            const int kw = tap - kh * 3;
            short8 a0 = *(const short8*)(Ab + tap * 4096);
            short8 a1 = *(const short8*)(Ab + tap * 4096 + 512);
            const char* bp = Bb + (kh * 66 + kw) * 16;
            short8 b0v = *(const short8*)bp;
            short8 b1v = *(const short8*)(bp + 512);
            acc[0][0] = __builtin_amdgcn_mfma_f32_32x32x16_bf16(a0, b0v, acc[0][0], 0, 0, 0);
            acc[1][0] = __builtin_amdgcn_mfma_f32_32x32x16_bf16(a1, b0v, acc[1][0], 0, 0, 0);
            acc[0][1] = __builtin_amdgcn_mfma_f32_32x32x16_bf16(a0, b1v, acc[0][1], 0, 0, 0);
            acc[1][1] = __builtin_amdgcn_mfma_f32_32x32x16_bf16(a1, b1v, acc[1][1], 0, 0, 0);
        }
    };

    // ---- pipeline ----
    issue_w(0);                   // W ci 0-31
    issue_x(xlds[0], 0);          // X ci 0-15
    issue_x(xlds[1], 1);          // X ci 16-31
    waitx();                      // drains W1 + X0; X1 in flight
    bar();
    compute(xlds[0], 0);          // phase 0
    bar();
    issue_x(xlds[0], 2);          // X ci 32-47
    waitx();                      // drains X1; X2 in flight
    bar();
    compute(xlds[1], 1);          // phase 1
    bar();
    issue_w(64);                  // W ci 32-63 (ws free now)
    issue_x(xlds[1], 3);          // X ci 48-63
    waitx();                      // drains X2 + W2; X3 in flight
    bar();
    compute(xlds[0], 0);          // phase 2
    asm volatile("s_waitcnt vmcnt(0)" ::: "memory");   // drain X3
    bar();
    compute(xlds[1], 1);          // phase 3

    // ---- epilogue: bias + store (full 128B line segments) ----
    const size_t ob = (size_t)bz * COUT_ * HW_ + (size_t)(y0 + w) * W_ + x0;
#pragma unroll
    for (int cg = 0; cg < 2; ++cg) {
#pragma unroll
        for (int g = 0; g < 16; ++g) {
            int co = cg * 32 + (g & 3) + 8 * (g >> 2) + 4 * lk;
            float bs = bias[co];
            out[ob + (size_t)co * HW_ + lp]      = acc[cg][0][g] + bs;
            out[ob + (size_t)co * HW_ + 32 + lp] = acc[cg][1][g] + bs;
        }
    }
}

extern "C" void kernel_launch(void* const* d_in, const int* in_sizes, int n_in,
                              void* d_out, int out_size, void* d_ws, size_t ws_size,
                              hipStream_t stream) {
    const float* x      = (const float*)d_in[0];
    const float* att    = (const float*)d_in[1];
    const float* weight = (const float*)d_in[2];
    const float* tb     = (const float*)d_in[3];
    const float* tq     = (const float*)d_in[4];
    const float* tn     = (const float*)d_in[5];
    const float* tx     = (const float*)d_in[6];
    const float* mb     = (const float*)d_in[7];
    const float* mq     = (const float*)d_in[8];
    const float* mn     = (const float*)d_in[9];
    const float* mx     = (const float*)d_in[10];
    const float* bias   = (const float*)d_in[11];

    unsigned short* aggb = (unsigned short*)d_ws;
    unsigned short* xT   = (unsigned short*)((unsigned char*)d_ws + WS_XT_OFF);
    float* outp = (float*)d_out;

    // blocks 0..8191: transpose; 8192..9343: weight aggregation (1152 blocks)
    prep_kernel<<<9344, 256, 0, stream>>>(
        x, att, weight, tb, tq, tn, tx, mb, mq, mn, mx, aggb, xT);

    conv_kernel<<<1024, 512, 0, stream>>>((const unsigned char*)d_ws, bias, outp);
}

// Round 7
// 93.347 us; speedup vs baseline: 2.4613x; 1.1289x over previous
//
#include <hip/hip_runtime.h>

#define B_    8
#define CIN_  64
#define COUT_ 64
#define H_    256
#define W_    256
#define HW_   65536

typedef __attribute__((ext_vector_type(8)))  short short8;    // 8 bf16 = 4 VGPRs
typedef __attribute__((ext_vector_type(16))) float f32x16;

static __device__ __forceinline__ unsigned short f2bf(float f) {
    union { float f; unsigned u; } v; v.f = f;
    unsigned r = (v.u + 0x7FFFu + ((v.u >> 16) & 1u)) >> 16;  // RNE
    return (unsigned short)r;
}

// async global->LDS, 16B per lane. LDS dest = wave-uniform base + lane*16.
static __device__ __forceinline__ void gload16(void* lds, const void* g) {
    __builtin_amdgcn_global_load_lds(
        (const __attribute__((address_space(1))) unsigned int*)g,
        (__attribute__((address_space(3))) unsigned int*)lds, 16, 0, 0);
}

// inline-asm barrier: also a compiler memory fence.
static __device__ __forceinline__ void bar() {
    asm volatile("s_barrier" ::: "memory");
}

// ws layout (bytes):
//   [0,       589824)  aggb2 [B][half(2)][tap(9)][ch(4)][co(64)][8ci] bf16
//   [589824,  589952)  zero pad (128 B)
//   [1048576, +64MiB)  xT2   [B][q(4)][pix(HW)][16ci] bf16
#define WS_PAD_OFF 589824
#define WS_XT_OFF  1048576

// ---------------------------------------------------------------------------
// Kernel 1 (fused): blocks 0..8191 transpose+convert x -> xT2 bf16;
// blocks 8192..9343 aggregate weights -> aggb2 bf16 + zero pad.
// ---------------------------------------------------------------------------
__global__ __launch_bounds__(256) void prep_kernel(
    const float* __restrict__ x,
    const float* __restrict__ att, const float* __restrict__ weight,
    const float* __restrict__ tb, const float* __restrict__ tq,
    const float* __restrict__ tn, const float* __restrict__ tx,
    const float* __restrict__ mb, const float* __restrict__ mq,
    const float* __restrict__ mn, const float* __restrict__ mx,
    unsigned short* __restrict__ aggb, unsigned short* __restrict__ xT)
{
    __shared__ unsigned short tile[64 * 72];   // transpose staging

    int bid = blockIdx.x;
    int t   = threadIdx.x;

    if (bid >= 8192) {                         // ---- weights part ----
        int idx = (bid - 8192) * 256 + t;
        if (idx < 64) aggb[294912 + idx] = 0;  // zero pad region (128 B)
        if (idx >= B_ * 9 * COUT_ * CIN_) return;
        int b    = idx / (9 * COUT_ * CIN_);
        int rem  = idx - b * (9 * COUT_ * CIN_);
        int tap  = rem / (COUT_ * CIN_);
        int rem2 = rem & (COUT_ * CIN_ - 1);
        int co   = rem2 >> 6;
        int ci   = rem2 & 63;
        int r  = (co * CIN_ + ci) * 9 + tap;   // [co][ci][kh][kw]
        int cc = co * CIN_ + ci;
        float a0 = att[b * 10 + 0];
        float a1 = att[b * 10 + 1];
        float a2 = att[b * 10 + 2];
        float val = weight[r]
                  + tb[r] * mb[cc] * a1
                  + tq[r] * mq[cc] * a2
                  + (tn[r] * mn[cc] + tx[r] * mx[cc]) * a0;
        // aggb2[b][half][tap][ch][co][8]: half=ci>>5, ch=(ci>>3)&3, o=ci&7
        int half = ci >> 5, ch = (ci >> 3) & 3, o = ci & 7;
        aggb[((((b * 2 + half) * 9 + tap) * 4 + ch) * 64 + co) * 8 + o] = f2bf(val);
        return;
    }

    // ---- transpose part: tile = 64 pixels x 64 ci of one batch ----
    int b  = bid >> 10;
    int p0 = (bid & 1023) << 6;
    int l  = t & 63;       // pixel lane
    int g  = t >> 6;       // wave -> ci group g*16..+15

    const float* xp = x + (((size_t)(b * CIN_ + g * 16)) << 16) + p0 + l;
    unsigned pk[8];
#pragma unroll
    for (int i = 0; i < 8; ++i) {
        float v0 = xp[(size_t)(2 * i) << 16];
        float v1 = xp[(size_t)(2 * i + 1) << 16];
        pk[i] = (unsigned)f2bf(v0) | ((unsigned)f2bf(v1) << 16);
    }
    *(uint4*)&tile[l * 72 + g * 16]     = make_uint4(pk[0], pk[1], pk[2], pk[3]);
    *(uint4*)&tile[l * 72 + g * 16 + 8] = make_uint4(pk[4], pk[5], pk[6], pk[7]);
    __syncthreads();

    // xT2[b][q][pix][16ci]: write ci-octet c of pixel p0+p at plane q=c>>1.
#pragma unroll
    for (int it = 0; it < 2; ++it) {
        int p = t >> 2;
        int c = (t & 3) + it * 4;              // ci octet 0..7
        uint4 v = *(const uint4*)&tile[p * 72 + c * 8];
        size_t off = (((size_t)(b * 4 + (c >> 1))) << 20)   // plane, in shorts (65536*16)
                   + (size_t)(p0 + p) * 16 + (c & 1) * 8;
        *(uint4*)&xT[off] = v;
    }
}

// ---------------------------------------------------------------------------
// Kernel 2: implicit-GEMM conv, 4-phase (16-ci) double-buffered pipeline.
// Block: 512 thr = 8 waves. Tile: 64 cout x (8 rows x 64 cols), one batch.
// LDS (79.9 KB -> 2 blocks/CU):
//   xlds[2][slot(672)][32B]: B operand. Chunk-XOR f(s)=(s>>1)&1 makes the
//     16B ds_read_b128 tile all 8 bank-quads 8x (conflict-free, any base),
//     while staging lanes cover a contiguous 1024B global span (coalesced).
//   wlds[tap(9)][ch(4)][co(64)][8ci]: A operand, contiguous reads; global
//     source aggb2 is linear in transfer index (fully coalesced).
// Pipeline per phase p: issue stage(p+1) -> vmcnt(newest) -> bar ->
// compute(p) -> bar  (loads stay in flight across compute).
// ---------------------------------------------------------------------------
__global__ __launch_bounds__(512, 4) void conv_kernel(
    const unsigned char* __restrict__ wsb,  // d_ws base
    const float* __restrict__ bias,         // [COUT]
    float* __restrict__ out)                // [B][COUT][H][W] fp32
{
    __shared__ __align__(16) unsigned short xlds[2][10752];  // 2 x 21504 B
    __shared__ __align__(16) unsigned short wlds[18432];     // 36864 B

    const int t = threadIdx.x;

    // XCD swizzle: 1024 blocks, xcd = bid&7 = batch.
    int bid = blockIdx.x;
    int bz  = bid & 7;            // batch
    int idx = bid >> 3;           // 0..127
    int ct  = idx >> 5;           // 0..3  col tile
    int rt  = idx & 31;           // 0..31 row tile
    const int x0 = ct * 64;
    const int y0 = rt * 8;

    const int l  = t & 63;
    const int w  = t >> 6;        // wave 0..7 -> output row
    const int lp = l & 31;        // pixel / co lane
    const int lk = l >> 5;        // k-half

    const unsigned char* wbB  = wsb + (size_t)bz * 73728;
    const unsigned char* xTB  = wsb + WS_XT_OFF + (size_t)bz * ((size_t)HW_ * CIN_ * 2);
    const unsigned char* zpad = wsb + WS_PAD_OFF;

    // ---- per-thread staging sources ----
    // X: transfer j = i*512+t (j<1344): slot s=j>>1, chunk ch'=j&1.
    //    LDS[s*32 + ch'*16] holds ci-octet (ch' ^ f(s)), f(s)=(s>>1)&1.
    //    src = xT2[pix(s)]*32 + (ch'^f)*16 (+ q*2MB per phase).
    const unsigned char* xsrc[3];
    bool xval[3];
#pragma unroll
    for (int i = 0; i < 3; ++i) {
        int j   = i * 512 + t;
        int s   = j >> 1;
        int ch  = j & 1;
        int row = s / 66;
        int col = s - row * 66;
        int gy  = y0 + row - 1;
        int gx  = x0 + col - 1;
        bool v  = (s < 660) && ((unsigned)gy < H_) && ((unsigned)gx < W_);
        xval[i] = v;
        int oct = ch ^ ((s >> 1) & 1);
        xsrc[i] = xTB + ((size_t)(gy * W_ + gx)) * 32 + (oct << 4);
    }
    // W: transfer j = i*512+t (j<2304): src = aggb2 + half*36864 + j*16 (linear).
    const unsigned char* wsrc[5];
#pragma unroll
    for (int i = 0; i < 5; ++i)
        wsrc[i] = wbB + (size_t)(i * 512 + t) * 16;

    auto issue_x = [&](unsigned short* buf, int qoff) {
        const unsigned char* s0 = xval[0] ? xsrc[0] + qoff : zpad;
        const unsigned char* s1 = xval[1] ? xsrc[1] + qoff : zpad;
        gload16((char*)buf + t * 16,        s0);
        gload16((char*)buf + 8192 + t * 16, s1);
        if (t < 320) {                                     // waves 0-4 only
            const unsigned char* s2 = xval[2] ? xsrc[2] + qoff : zpad;
            gload16((char*)buf + 16384 + t * 16, s2);
        }
    };
    auto issue_w = [&](int hoff) {
        gload16((char*)wlds + t * 16,         wsrc[0] + hoff);
        gload16((char*)wlds + 8192 + t * 16,  wsrc[1] + hoff);
        gload16((char*)wlds + 16384 + t * 16, wsrc[2] + hoff);
        gload16((char*)wlds + 24576 + t * 16, wsrc[3] + hoff);
        if (t < 256)                                       // waves 0-3 only
            gload16((char*)wlds + 32768 + t * 16, wsrc[4] + hoff);
    };
    // Wait so that only the newest X batch may remain in flight.
    auto waitx = [&]() {
        if (t < 320) { asm volatile("s_waitcnt vmcnt(3)" ::: "memory"); }
        else         { asm volatile("s_waitcnt vmcnt(2)" ::: "memory"); }
    };

    f32x16 acc[2][2];             // [co-group][pixel-group]
#pragma unroll
    for (int i = 0; i < 16; ++i) {
        acc[0][0][i] = 0.f; acc[0][1][i] = 0.f;
        acc[1][0][i] = 0.f; acc[1][1][i] = 0.f;
    }

    const int sB0 = w * 66 + lp;

    // compute one 16-ci phase from buffer `buf`, W k-half h (0=lo,1=hi).
    auto compute = [&](const unsigned short* buf, const int h) {
        const char* Ab = (const char*)wlds + h * 2048 + lk * 1024 + lp * 16;
        __builtin_amdgcn_s_setprio(1);
#pragma unroll
        for (int tap = 0; tap < 9; ++tap) {
            const int kh = tap / 3;
            const int kw = tap - kh * 3;
            short8 a0 = *(const short8*)(Ab + tap * 4096);
            short8 a1 = *(const short8*)(Ab + tap * 4096 + 512);
#pragma unroll
            for (int pb = 0; pb < 2; ++pb) {
                int s    = sB0 + kh * 66 + kw + pb * 32;
                int boff = (s * 32 + (lk << 4)) ^ ((s & 2) << 3);
                short8 bv = *(const short8*)((const char*)buf + boff);
                acc[0][pb] = __builtin_amdgcn_mfma_f32_32x32x16_bf16(a0, bv, acc[0][pb], 0, 0, 0);
                acc[1][pb] = __builtin_amdgcn_mfma_f32_32x32x16_bf16(a1, bv, acc[1][pb], 0, 0, 0);
            }
        }
        __builtin_amdgcn_s_setprio(0);
    };

    // ---- pipeline ----
    issue_w(0);                   // W ci 0-31
    issue_x(xlds[0], 0);          // X q0 (ci 0-15)
    issue_x(xlds[1], 2097152);    // X q1 (ci 16-31)
    waitx();                      // drains W1 + X0; X1 in flight
    bar();
    compute(xlds[0], 0);          // phase 0
    bar();
    issue_x(xlds[0], 4194304);    // X q2 (ci 32-47)
    waitx();                      // drains X1; X2 in flight
    bar();
    compute(xlds[1], 1);          // phase 1
    bar();
    issue_w(36864);               // W ci 32-63 (wlds free now)
    issue_x(xlds[1], 6291456);    // X q3 (ci 48-63)
    waitx();                      // drains X2 + W2; X3 in flight
    bar();
    compute(xlds[0], 0);          // phase 2
    asm volatile("s_waitcnt vmcnt(0)" ::: "memory");   // drain X3
    bar();
    compute(xlds[1], 1);          // phase 3

    // ---- epilogue: bias + store (full 128B line segments) ----
    const size_t ob = (size_t)bz * COUT_ * HW_ + (size_t)(y0 + w) * W_ + x0;
#pragma unroll
    for (int cg = 0; cg < 2; ++cg) {
#pragma unroll
        for (int g = 0; g < 16; ++g) {
            int co = cg * 32 + (g & 3) + 8 * (g >> 2) + 4 * lk;
            float bs = bias[co];
            out[ob + (size_t)co * HW_ + lp]      = acc[cg][0][g] + bs;
            out[ob + (size_t)co * HW_ + 32 + lp] = acc[cg][1][g] + bs;
        }
    }
}

extern "C" void kernel_launch(void* const* d_in, const int* in_sizes, int n_in,
                              void* d_out, int out_size, void* d_ws, size_t ws_size,
                              hipStream_t stream) {
    const float* x      = (const float*)d_in[0];
    const float* att    = (const float*)d_in[1];
    const float* weight = (const float*)d_in[2];
    const float* tb     = (const float*)d_in[3];
    const float* tq     = (const float*)d_in[4];
    const float* tn     = (const float*)d_in[5];
    const float* tx     = (const float*)d_in[6];
    const float* mb     = (const float*)d_in[7];
    const float* mq     = (const float*)d_in[8];
    const float* mn     = (const float*)d_in[9];
    const float* mx     = (const float*)d_in[10];
    const float* bias   = (const float*)d_in[11];

    unsigned short* aggb = (unsigned short*)d_ws;
    unsigned short* xT   = (unsigned short*)((unsigned char*)d_ws + WS_XT_OFF);
    float* outp = (float*)d_out;

    // blocks 0..8191: transpose; 8192..9343: weight aggregation (1152 blocks)
    prep_kernel<<<9344, 256, 0, stream>>>(
        x, att, weight, tb, tq, tn, tx, mb, mq, mn, mx, aggb, xT);

    conv_kernel<<<1024, 512, 0, stream>>>((const unsigned char*)d_ws, bias, outp);
}